// Round 9
// baseline (252.618 us; speedup 1.0000x reference)
//
#include <hip/hip_runtime.h>

#define B_    32
#define L_    4096
#define DIN   150
#define DST   75
#define HID   75
#define HPAD  80
#define INF30 1e30f
#define SPART 152   // per-chunk partial: t[150], z, m

// ws: W0p[12000] W1p[80] sp[2560] part[2048*152] cnt[32]

__device__ __forceinline__ float tanh_fast(float p) {
    float e = __expf(-2.f * fabsf(p));
    float t = (1.f - e) / (1.f + e);
    return copysignf(t, p);
}

__global__ __launch_bounds__(256) void k_prep(
    const float* __restrict__ W0, const float* __restrict__ W1,
    const float* __restrict__ state, const float* __restrict__ b0,
    float* __restrict__ W0p, float* __restrict__ W1p,
    float* __restrict__ sp, int* __restrict__ cnt) {
    int blk = blockIdx.x, tid = threadIdx.x;
    if (blk < 47) {
        int i = blk * 256 + tid;
        if (i < DIN * HPAD) {
            int d = i / HPAD, h = i - d * HPAD;
            W0p[i] = (h < HID) ? W0[(DST + d) * HID + h] : 0.f;
        }
    } else if (blk == 47) {
        if (tid < HPAD) W1p[tid] = (tid < HID) ? W1[tid] : 0.f;
        if (tid >= 128 && tid < 128 + B_) cnt[tid - 128] = 0;
    } else {
        int idx = (blk - 48) * 256 + tid;     // 0..2559
        if (idx < B_ * HPAD) {
            int b = idx / HPAD, h = idx - b * HPAD;
            float acc = 0.f;
            if (h < HID) {
                acc = b0[h];
                #pragma unroll 5
                for (int k = 0; k < DST; ++k)
                    acc = fmaf(state[b * DST + k], W0[k * HID + h], acc);
            }
            sp[idx] = acc;
        }
    }
}

// Fused: 64-row scorer GEMM + s1 + chunk softmax partials + last-block combine.
// XT additive swizzle: phys = k*64 + ((((r>>2) + k + (k>>2)) & 15)<<2) + (r&3)
//  - stage writes: lanes step k by 4 -> slot step 5 mod 16 = bijective (no conflict)
//  - GEMM reads (k fixed): slots = rg + const mod 16, bijective
//  - only inherent 2-row b128 alias remains (~free, m136)
__global__ __launch_bounds__(256, 4) void k_fused(
    const float* __restrict__ in, const unsigned char* __restrict__ maskB,
    const float* __restrict__ W0p, const float* __restrict__ W1p,
    const float* __restrict__ b1, const float* __restrict__ sp,
    float* __restrict__ s1out, float* __restrict__ part,
    int* __restrict__ cnt, float* __restrict__ res) {
    __shared__ __align__(16) float XT[DIN * 64];   // 38400 B
    __shared__ __align__(16) float sred2[4 * 64 + 2];
    __shared__ __align__(16) float wvals[64];
    __shared__ int ticket;

    int blk = blockIdx.x, tid = threadIdx.x;
    int b = blk >> 6, l0 = (blk & 63) << 6;
    const float4* src4 = (const float4*)(in + (size_t)(b * L_ + l0) * DIN);

    // ---- stage x -> XT (transposed + additive swizzle)
    #pragma unroll
    for (int p = 0; p < 10; ++p) {
        int i4 = p * 256 + tid;
        if (i4 < 2400) {
            float4 v = src4[i4];
            int idx = i4 << 2;
            float vals[4] = {v.x, v.y, v.z, v.w};
            #pragma unroll
            for (int e = 0; e < 4; ++e) {
                int id = idx + e;
                int r = id / DIN;
                int k = id - r * DIN;
                int slot = ((r >> 2) + k + (k >> 2)) & 15;
                XT[(k << 6) + (slot << 2) + (r & 3)] = vals[e];
            }
        }
    }
    __syncthreads();

    // ---- GEMM: thread (rg,cg) = rows 4rg..4rg+3 x cols {4cg..4cg+3, 64+cg}
    int rg = tid & 15, cg = tid >> 4;
    float acc[4][5];
    {
        float s0 = sp[b * HPAD + (cg << 2) + 0];
        float s1_ = sp[b * HPAD + (cg << 2) + 1];
        float s2 = sp[b * HPAD + (cg << 2) + 2];
        float s3 = sp[b * HPAD + (cg << 2) + 3];
        float s4 = sp[b * HPAD + 64 + cg];
        #pragma unroll
        for (int j = 0; j < 4; ++j) {
            acc[j][0] = s0; acc[j][1] = s1_; acc[j][2] = s2;
            acc[j][3] = s3; acc[j][4] = s4;
        }
    }
    const float* wb4 = W0p + (cg << 2);
    const float* wb1 = W0p + 64 + cg;
    #pragma unroll 6
    for (int k = 0; k < DIN; ++k) {
        int slot = (rg + k + (k >> 2)) & 15;
        float4 xv = *(const float4*)&XT[(k << 6) + (slot << 2)];
        float4 wv = *(const float4*)&wb4[k * HPAD];
        float  w4 = wb1[k * HPAD];
        float xj[4] = {xv.x, xv.y, xv.z, xv.w};
        #pragma unroll
        for (int j = 0; j < 4; ++j) {
            acc[j][0] = fmaf(xj[j], wv.x, acc[j][0]);
            acc[j][1] = fmaf(xj[j], wv.y, acc[j][1]);
            acc[j][2] = fmaf(xj[j], wv.z, acc[j][2]);
            acc[j][3] = fmaf(xj[j], wv.w, acc[j][3]);
            acc[j][4] = fmaf(xj[j], w4,   acc[j][4]);
        }
    }

    // ---- tanh + W1 contract; reduce across cg (xor16/32 within wave)
    float w1a = W1p[(cg << 2) + 0], w1b = W1p[(cg << 2) + 1];
    float w1c = W1p[(cg << 2) + 2], w1d = W1p[(cg << 2) + 3];
    float w1e = W1p[64 + cg];
    int wv_ = tid >> 6, lane = tid & 63;
    float spart[4];
    #pragma unroll
    for (int j = 0; j < 4; ++j) {
        float s = 0.f;
        s = fmaf(tanh_fast(acc[j][0]), w1a, s);
        s = fmaf(tanh_fast(acc[j][1]), w1b, s);
        s = fmaf(tanh_fast(acc[j][2]), w1c, s);
        s = fmaf(tanh_fast(acc[j][3]), w1d, s);
        s = fmaf(tanh_fast(acc[j][4]), w1e, s);
        s += __shfl_xor(s, 16, 64);
        s += __shfl_xor(s, 32, 64);
        spart[j] = s;
    }
    if (lane < 16) {
        #pragma unroll
        for (int j = 0; j < 4; ++j)
            sred2[(wv_ << 6) + (lane << 2) + j] = spart[j];
    }
    __syncthreads();

    // ---- final s, mask, s1 write, chunk-local softmax stats (wave 0)
    if (tid < 64) {
        float s = b1[0] + sred2[tid] + sred2[64 + tid]
                + sred2[128 + tid] + sred2[192 + tid];
        unsigned char probe = maskB[tid * 4 + 1];   // dtype autodetect
        bool isI32 = __all(probe == 0);
        int l = l0 + tid;
        bool mv = isI32 ? (((const int*)maskB)[b * L_ + l] != 0)
                        : (maskB[b * L_ + l] != 0);
        float s1v = s - (mv ? 0.f : INF30);
        s1out[b * L_ + l] = s1v;
        float mx = s1v;
        #pragma unroll
        for (int off = 1; off < 64; off <<= 1)
            mx = fmaxf(mx, __shfl_xor(mx, off, 64));
        float wexp = __expf(s1v - mx);
        wvals[tid] = wexp;
        float z = wexp;
        #pragma unroll
        for (int off = 1; off < 64; off <<= 1) z += __shfl_xor(z, off, 64);
        if (tid == 0) {
            part[(size_t)blk * SPART + 150] = z;
            part[(size_t)blk * SPART + 151] = mx;
        }
    }
    __syncthreads();

    // ---- phase C: t[d] = sum_l wvals[l] * x[l][d] from resident XT
    if (tid < DIN) {
        float t0 = 0.f, t1 = 0.f, t2 = 0.f, t3 = 0.f;
        #pragma unroll
        for (int lq = 0; lq < 16; ++lq) {
            int slot = (lq + tid + (tid >> 2)) & 15;
            float4 xt = *(const float4*)&XT[(tid << 6) + (slot << 2)];
            float4 wq = *(const float4*)&wvals[lq << 2];
            t0 = fmaf(xt.x, wq.x, t0);
            t1 = fmaf(xt.y, wq.y, t1);
            t2 = fmaf(xt.z, wq.z, t2);
            t3 = fmaf(xt.w, wq.w, t3);
        }
        part[(size_t)blk * SPART + tid] = (t0 + t1) + (t2 + t3);
    }

    // ---- completion ticket (split-K pattern, G16 device-scope fences)
    __syncthreads();
    if (tid == 0) {
        __threadfence();                       // release: flush part writes
        ticket = atomicAdd(&cnt[b], 1);
    }
    __syncthreads();
    if (ticket != 63) return;
    __threadfence();                           // acquire: see remote XCD writes

    // ---- combine for batch b (this block only)
    const float* pb = part + (size_t)(b << 6) * SPART;
    if (tid < 64) {
        float mc = pb[(size_t)tid * SPART + 151];
        float mm = mc;
        #pragma unroll
        for (int off = 1; off < 64; off <<= 1)
            mm = fmaxf(mm, __shfl_xor(mm, off, 64));
        float e = __expf(mc - mm);
        sred2[tid] = e;                        // esh[c]
        float zp = pb[(size_t)tid * SPART + 150] * e;
        #pragma unroll
        for (int off = 1; off < 64; off <<= 1) zp += __shfl_xor(zp, off, 64);
        if (tid == 0) sred2[256] = zp;         // Z
    }
    __syncthreads();
    if (tid < DIN) {
        float Z = sred2[256];
        float ts = 0.f;
        #pragma unroll 8
        for (int c = 0; c < 64; ++c)
            ts = fmaf(pb[(size_t)c * SPART + tid], sred2[c], ts);
        res[b * DIN + tid] = ts / Z;
    }
}

extern "C" void kernel_launch(void* const* d_in, const int* in_sizes, int n_in,
                              void* d_out, int out_size, void* d_ws, size_t ws_size,
                              hipStream_t stream) {
    const float*         inputs = (const float*)d_in[0];
    const float*         state  = (const float*)d_in[1];
    const unsigned char* cmask  = (const unsigned char*)d_in[2];
    const float*         W0     = (const float*)d_in[3];
    const float*         b0     = (const float*)d_in[4];
    const float*         W1     = (const float*)d_in[5];
    const float*         b1     = (const float*)d_in[6];

    float* res  = (float*)d_out;             // B*1*DIN
    float* s1   = (float*)d_out + B_ * DIN;  // B*L
    float* wsf  = (float*)d_ws;
    float* W0p  = wsf;                       // 12000
    float* W1p  = W0p + DIN * HPAD;          // 80
    float* sp   = W1p + HPAD;                // 2560
    float* part = sp + B_ * HPAD;            // 2048*152
    int*   cnt  = (int*)(part + 2048 * SPART);  // 32

    k_prep<<<58, 256, 0, stream>>>(W0, W1, state, b0, W0p, W1p, sp, cnt);
    k_fused<<<B_ * L_ / 64, 256, 0, stream>>>(inputs, cmask, W0p, W1p, b1, sp,
                                              s1, part, cnt, res);
}

// Round 10
// 203.232 us; speedup vs baseline: 1.2430x; 1.2430x over previous
//
#include <hip/hip_runtime.h>

#define B_    32
#define L_    4096
#define DIN   150
#define DST   75
#define HID   75
#define HPAD  80
#define INF30 1e30f

// ws: W0p[12000] W1p[80] sp[2560] part_t[32*152*64]
// part_t layout: [b][field(0..149=t_d,150=z,151=m)][chunk 0..63]

__device__ __forceinline__ float tanh_fast(float p) {
    float e = __expf(-2.f * fabsf(p));
    float t = (1.f - e) / (1.f + e);
    return copysignf(t, p);
}

__global__ __launch_bounds__(256) void k_prep(
    const float* __restrict__ W0, const float* __restrict__ W1,
    const float* __restrict__ state, const float* __restrict__ b0,
    float* __restrict__ W0p, float* __restrict__ W1p,
    float* __restrict__ sp) {
    int blk = blockIdx.x, tid = threadIdx.x;
    if (blk < 47) {
        int i = blk * 256 + tid;
        if (i < DIN * HPAD) {
            int d = i / HPAD, h = i - d * HPAD;
            W0p[i] = (h < HID) ? W0[(DST + d) * HID + h] : 0.f;
        }
    } else if (blk == 47) {
        if (tid < HPAD) W1p[tid] = (tid < HID) ? W1[tid] : 0.f;
    } else {
        int idx = (blk - 48) * 256 + tid;     // 0..2559
        if (idx < B_ * HPAD) {
            int b = idx / HPAD, h = idx - b * HPAD;
            float acc = 0.f;
            if (h < HID) {
                acc = b0[h];
                #pragma unroll 5
                for (int k = 0; k < DST; ++k)
                    acc = fmaf(state[b * DST + k], W0[k * HID + h], acc);
            }
            sp[idx] = acc;
        }
    }
}

// 128 threads = 2 waves; 64 rows/block; thread tile = 8 rows x 5 cols.
// XT[k][r] additive-swizzled: phys = k*64 + slot(g,k)*4 + (r&3),
//   g = r>>2, slot = (g + k + (k>>2)) & 15.
//   - GEMM reads: 8 distinct group-addresses per wave (8 rg x 8 cg broadcast)
//     -> 2-way bank alias max = free (m136).
//   - staging writes: k strides 4 per lane -> slot stride 5 mod 16, bijective.
__global__ __launch_bounds__(128, 2) void k_main(
    const float* __restrict__ in, const unsigned char* __restrict__ maskB,
    const float* __restrict__ W0p, const float* __restrict__ W1p,
    const float* __restrict__ b1, const float* __restrict__ sp,
    float* __restrict__ s1out, float* __restrict__ part_t) {
    __shared__ __align__(16) float XT[DIN * 64];   // 38400 B
    __shared__ __align__(16) float sred[2 * 64];
    __shared__ __align__(16) float wvals[64];

    int blk = blockIdx.x, tid = threadIdx.x;
    int b = blk >> 6, c = blk & 63, l0 = c << 6;
    const float4* src4 = (const float4*)(in + (size_t)(b * L_ + l0) * DIN);

    // ---- stage x -> XT (transposed + swizzled); 2400 float4 loads
    for (int p = 0; p < 19; ++p) {
        int i4 = p * 128 + tid;
        if (i4 < 2400) {
            float4 v = src4[i4];
            int idx = i4 << 2;
            float vals[4] = {v.x, v.y, v.z, v.w};
            #pragma unroll
            for (int e = 0; e < 4; ++e) {
                int id = idx + e;
                int r = id / DIN;
                int k = id - r * DIN;
                int slot = ((r >> 2) + k + (k >> 2)) & 15;
                XT[(k << 6) + (slot << 2) + (r & 3)] = vals[e];
            }
        }
    }
    __syncthreads();

    // ---- GEMM: thread (rg,cg): rows {8rg..8rg+7} x cols {4cg..4cg+3, 64+cg}
    int rg = tid & 7, cg = tid >> 3;               // rg 0..7, cg 0..15
    float acc[8][5];
    {
        float s0 = sp[b * HPAD + (cg << 2) + 0];
        float s1_ = sp[b * HPAD + (cg << 2) + 1];
        float s2 = sp[b * HPAD + (cg << 2) + 2];
        float s3 = sp[b * HPAD + (cg << 2) + 3];
        float s4 = sp[b * HPAD + 64 + cg];
        #pragma unroll
        for (int j = 0; j < 8; ++j) {
            acc[j][0] = s0; acc[j][1] = s1_; acc[j][2] = s2;
            acc[j][3] = s3; acc[j][4] = s4;
        }
    }
    const float* wb4 = W0p + (cg << 2);
    const float* wb1 = W0p + 64 + cg;
    #pragma unroll 6
    for (int k = 0; k < DIN; ++k) {
        int kc = k + (k >> 2);
        float4 xa = *(const float4*)&XT[(k << 6) + ((((rg << 1) + kc) & 15) << 2)];
        float4 xb = *(const float4*)&XT[(k << 6) + ((((rg << 1) + 1 + kc) & 15) << 2)];
        float4 wv = *(const float4*)&wb4[k * HPAD];
        float  w4 = wb1[k * HPAD];
        float xj[8] = {xa.x, xa.y, xa.z, xa.w, xb.x, xb.y, xb.z, xb.w};
        #pragma unroll
        for (int j = 0; j < 8; ++j) {
            acc[j][0] = fmaf(xj[j], wv.x, acc[j][0]);
            acc[j][1] = fmaf(xj[j], wv.y, acc[j][1]);
            acc[j][2] = fmaf(xj[j], wv.z, acc[j][2]);
            acc[j][3] = fmaf(xj[j], wv.w, acc[j][3]);
            acc[j][4] = fmaf(xj[j], w4,   acc[j][4]);
        }
    }

    // ---- tanh + W1 contract; butterfly over 8 cg within wave
    float w1a = W1p[(cg << 2) + 0], w1b = W1p[(cg << 2) + 1];
    float w1c = W1p[(cg << 2) + 2], w1d = W1p[(cg << 2) + 3];
    float w1e = W1p[64 + cg];
    int wv_ = tid >> 6, lane = tid & 63;
    #pragma unroll
    for (int j = 0; j < 8; ++j) {
        float s = 0.f;
        s = fmaf(tanh_fast(acc[j][0]), w1a, s);
        s = fmaf(tanh_fast(acc[j][1]), w1b, s);
        s = fmaf(tanh_fast(acc[j][2]), w1c, s);
        s = fmaf(tanh_fast(acc[j][3]), w1d, s);
        s = fmaf(tanh_fast(acc[j][4]), w1e, s);
        s += __shfl_xor(s, 8, 64);
        s += __shfl_xor(s, 16, 64);
        s += __shfl_xor(s, 32, 64);
        if (lane < 8)                       // lane==rg, cgl==0
            sred[(wv_ << 6) + (lane << 3) + j] = s;
    }
    __syncthreads();

    // ---- final s, mask, s1 write, chunk stats (wave 0)
    if (tid < 64) {
        float s = b1[0] + sred[tid] + sred[64 + tid];
        unsigned char probe = maskB[tid * 4 + 1];   // dtype autodetect
        bool isI32 = __all(probe == 0);
        int l = l0 + tid;
        bool mv = isI32 ? (((const int*)maskB)[b * L_ + l] != 0)
                        : (maskB[b * L_ + l] != 0);
        float s1v = s - (mv ? 0.f : INF30);
        s1out[b * L_ + l] = s1v;
        float mx = s1v;
        #pragma unroll
        for (int off = 1; off < 64; off <<= 1)
            mx = fmaxf(mx, __shfl_xor(mx, off, 64));
        float wexp = __expf(s1v - mx);
        wvals[tid] = wexp;
        float z = wexp;
        #pragma unroll
        for (int off = 1; off < 64; off <<= 1) z += __shfl_xor(z, off, 64);
        if (tid == 0) {
            part_t[((size_t)b * 152 + 150) * 64 + c] = z;
            part_t[((size_t)b * 152 + 151) * 64 + c] = mx;
        }
    }
    __syncthreads();

    // ---- phase C: t[d] = sum_r wvals[r] * x[r][d] from resident XT
    for (int d = tid; d < DIN; d += 128) {
        float t0 = 0.f, t1 = 0.f, t2 = 0.f, t3 = 0.f;
        int dc = d + (d >> 2);
        #pragma unroll
        for (int lq = 0; lq < 16; ++lq) {
            int slot = (lq + dc) & 15;
            float4 xt = *(const float4*)&XT[(d << 6) + (slot << 2)];
            float4 wq = *(const float4*)&wvals[lq << 2];
            t0 = fmaf(xt.x, wq.x, t0);
            t1 = fmaf(xt.y, wq.y, t1);
            t2 = fmaf(xt.z, wq.z, t2);
            t3 = fmaf(xt.w, wq.w, t3);
        }
        part_t[((size_t)b * 152 + d) * 64 + c] = (t0 + t1) + (t2 + t3);
    }
}

// res[b][d] = sum_c t_c[d] e^{m_c-M} / sum_c z_c e^{m_c-M}
// part_t reads are contiguous 256B runs per thread (L2-resident).
__global__ __launch_bounds__(192) void k_combine(
    const float* __restrict__ part_t, float* __restrict__ res) {
    int b = blockIdx.x, tid = threadIdx.x;
    __shared__ __align__(16) float esh[64];
    __shared__ float Zsh;
    if (tid < 64) {
        float mc = part_t[((size_t)b * 152 + 151) * 64 + tid];
        float mm = mc;
        #pragma unroll
        for (int off = 1; off < 64; off <<= 1)
            mm = fmaxf(mm, __shfl_xor(mm, off, 64));
        float e = __expf(mc - mm);
        esh[tid] = e;
        float zp = part_t[((size_t)b * 152 + 150) * 64 + tid] * e;
        #pragma unroll
        for (int off = 1; off < 64; off <<= 1) zp += __shfl_xor(zp, off, 64);
        if (tid == 0) Zsh = zp;
    }
    __syncthreads();
    if (tid < DIN) {
        const float* pd = part_t + ((size_t)b * 152 + tid) * 64;
        float t0 = 0.f, t1 = 0.f, t2 = 0.f, t3 = 0.f;
        #pragma unroll
        for (int c4 = 0; c4 < 16; ++c4) {
            float4 pv = *(const float4*)&pd[c4 << 2];
            float4 ev = *(const float4*)&esh[c4 << 2];
            t0 = fmaf(pv.x, ev.x, t0);
            t1 = fmaf(pv.y, ev.y, t1);
            t2 = fmaf(pv.z, ev.z, t2);
            t3 = fmaf(pv.w, ev.w, t3);
        }
        res[b * DIN + tid] = ((t0 + t1) + (t2 + t3)) / Zsh;
    }
}

extern "C" void kernel_launch(void* const* d_in, const int* in_sizes, int n_in,
                              void* d_out, int out_size, void* d_ws, size_t ws_size,
                              hipStream_t stream) {
    const float*         inputs = (const float*)d_in[0];
    const float*         state  = (const float*)d_in[1];
    const unsigned char* cmask  = (const unsigned char*)d_in[2];
    const float*         W0     = (const float*)d_in[3];
    const float*         b0     = (const float*)d_in[4];
    const float*         W1     = (const float*)d_in[5];
    const float*         b1     = (const float*)d_in[6];

    float* res   = (float*)d_out;             // B*1*DIN
    float* s1    = (float*)d_out + B_ * DIN;  // B*L
    float* wsf   = (float*)d_ws;
    float* W0p   = wsf;                       // 12000
    float* W1p   = W0p + DIN * HPAD;          // 80
    float* sp    = W1p + HPAD;                // 2560
    float* partT = sp + B_ * HPAD;            // 32*152*64

    k_prep<<<58, 256, 0, stream>>>(W0, W1, state, b0, W0p, W1p, sp);
    k_main<<<B_ * L_ / 64, 128, 0, stream>>>(inputs, cmask, W0p, W1p, b1, sp,
                                             s1, partT);
    k_combine<<<B_, 192, 0, stream>>>(partT, res);
}